// Round 10
// baseline (550.323 us; speedup 1.0000x reference)
//
#include <hip/hip_runtime.h>

// ---------------------------------------------------------------------------
// DecoderLayer (B=2, S=T=2048, D=1024, H=16, DK=64, DF=4096).
// fp32 interface; internal bf16 MFMA. ws = 72 MB:
//   P0..P4 : 5 x 8 MB activation slots
//   Wb     : 32 MB bf16 weights (converted once per launch by conv_all)
// d_out doubles as 16 MB bf16 scratch (F2) until the final LN.
// GEMMs v9: 3-buffer LDS ring, counted vmcnt, ONE barrier per K-step.
//   TM=128: BK=32 (48 KB ring).  TM=64: BK=64 (72 KB ring).
// flash_attn v8: KVBLK=64 — two 32-key subtiles per barrier step, ring3,
//   counted vmcnt(4). No-max softmax p = exp2(st) (Q pre-scaled by log2e/8).
// ---------------------------------------------------------------------------

typedef __bf16 bf16_t;
typedef bf16_t  bf16x8 __attribute__((ext_vector_type(8)));
typedef float   f32x4  __attribute__((ext_vector_type(4)));
typedef unsigned short ushort_t;
typedef ushort_t u16x8 __attribute__((ext_vector_type(8)));
typedef ushort_t u16x4 __attribute__((ext_vector_type(4)));

__device__ __forceinline__ float b2f(ushort_t u) {
    union { unsigned u; float f; } x; x.u = ((unsigned)u) << 16; return x.f;
}
__device__ __forceinline__ ushort_t f2b(float f) {     // RNE
    union { float f; unsigned u; } x; x.f = f;
    unsigned r = x.u + 0x7fffu + ((x.u >> 16) & 1u);
    return (ushort_t)(r >> 16);
}
__device__ __forceinline__ unsigned pk2(float lo, float hi) {
    union { float f; unsigned u; } a, b; a.f = lo; b.f = hi;
    return (b.u & 0xffff0000u) | (a.u >> 16);
}

#if __has_builtin(__builtin_amdgcn_exp2f)
#define EXP2(x) __builtin_amdgcn_exp2f(x)
#else
#define EXP2(x) exp2f(x)
#endif

// global -> LDS direct, 16B per lane (LDS dest = wave-uniform base + lane*16)
#define GLL(gp, lp)                                                            \
    __builtin_amdgcn_global_load_lds(                                          \
        (const __attribute__((address_space(1))) void*)(gp),                   \
        (__attribute__((address_space(3))) void*)(lp), 16, 0, 0)

// ---------------------------------------------------------------------------
// conv_all: fp32 -> bf16 (truncation). 12288 blocks x 256 thr x 8 elems.
// ---------------------------------------------------------------------------
__global__ __launch_bounds__(256) void conv_all(
    const float* __restrict__ x,   const float* __restrict__ enc,
    const float* __restrict__ w0, const float* __restrict__ w1,
    const float* __restrict__ w2, const float* __restrict__ w3,
    const float* __restrict__ w4, const float* __restrict__ w5,
    const float* __restrict__ w6, const float* __restrict__ w7,
    const float* __restrict__ wf1, const float* __restrict__ wf2,
    ushort_t* __restrict__ Xb, ushort_t* __restrict__ Eb,
    ushort_t* __restrict__ Wb)
{
    const int b = blockIdx.x;
    const float* src;
    ushort_t* dst;
    size_t blk;
    if (b < 2048)      { src = x;   dst = Xb; blk = b; }
    else if (b < 4096) { src = enc; dst = Eb; blk = b - 2048; }
    else if (b < 8192) {
        const int i = (b - 4096) >> 9;
        src = (i < 4) ? (i < 2 ? (i == 0 ? w0 : w1) : (i == 2 ? w2 : w3))
                      : (i < 6 ? (i == 4 ? w4 : w5) : (i == 6 ? w6 : w7));
        dst = Wb + (size_t)i * 1048576;
        blk = (b - 4096) & 511;
    }
    else if (b < 10240) { src = wf1; dst = Wb + (size_t)8  * 1048576; blk = b - 8192; }
    else                { src = wf2; dst = Wb + (size_t)12 * 1048576; blk = b - 10240; }

    const size_t e = blk * 2048 + (size_t)threadIdx.x * 8;
    const float4 a = *(const float4*)(src + e);
    const float4 c = *(const float4*)(src + e + 4);
    uint4 r;
    r.x = pk2(a.x, a.y); r.y = pk2(a.z, a.w);
    r.z = pk2(c.x, c.y); r.w = pk2(c.z, c.w);
    *(uint4*)(dst + e) = r;
}

// ---------------------------------------------------------------------------
// GEMM v9: A[M,K] @ W[N,K]^T + bias (all bf16). TM x 128 tile.
// TM=128: BK=32, ring3, vmcnt(4).  TM=64: BK=64, ring3, vmcnt(6).
// One barrier per K-step. XCD-aware block remap.
// EPI=1: permute-store -> [B,H,S,64] slot (+ (bn>>10)*4M if FUSED)
//   TRV: last 1024-col region stores V TRANSPOSED [B,H,64,S].
//   QSC: which==0 region (the Q projection) is pre-scaled by log2(e)/8.
// EPI=2: + residual (RF32: fp32 residual)    EPI=3: ReLU
// ---------------------------------------------------------------------------
template <int EPI, int TM, bool RF32, bool FUSED, bool SPLITA, bool SPLITC,
          bool TRV, bool QSC>
__global__ __launch_bounds__(256) void gemm_bt(
    const ushort_t* __restrict__ A, const ushort_t* __restrict__ A2,
    const ushort_t* __restrict__ W,
    const float* __restrict__ b1, const float* __restrict__ b2,
    const float* __restrict__ b3,
    const void* __restrict__ Rv,
    ushort_t* __restrict__ C, ushort_t* __restrict__ C2,
    int M, int N, int K)
{
    constexpr int IM = TM / 32;                  // acc rows per wave
    constexpr int NKS = (TM == 128) ? 1 : 2;     // 32-wide K-subtiles per step
    constexpr int ASLOT = NKS * TM * 32;
    constexpr int BSLOT = NKS * 128 * 32;
    __shared__ __align__(16) ushort_t At[3][ASLOT];
    __shared__ __align__(16) ushort_t Bt[3][BSLOT];

    const int tid  = threadIdx.x;
    const int lane = tid & 63, w = tid >> 6;
    const int g = lane >> 4, qi = lane & 15;

    // XCD-aware remap (bijective; nbm is a multiple of 8 for all our grids)
    const int nbn = gridDim.x, nbm = gridDim.y;
    const int lin = blockIdx.x + nbn * blockIdx.y;
    const int xcd = lin & 7, j = lin >> 3;
    const int bpx = nbm >> 3;                   // bm-blocks per xcd
    const int bmb = xcd * bpx + (j & (bpx - 1));
    const int bnb = j / bpx;
    const int bm = bmb * TM, bn = bnb * 128;

    const int wm = (w >> 1) * (TM / 2), wn = (w & 1) * 64;

    const ushort_t* Ap = SPLITA ? ((bm < 2048) ? A : A2) : A;
    const int       am = SPLITA ? (bm & 2047) : bm;

    const int srow = lane >> 2;          // row within a 16-row segment
    const int scol = (lane & 3) * 8;     // bf16 col within 32

    f32x4 acc[IM][4] = {};

    const int niter = (TM == 128) ? (K >> 5) : (K >> 6);   // >= 16 always

    // stage K-step kt into ring buffer c
    auto stage = [&](int kt, int c) {
        if constexpr (TM == 128) {
            const int k0s = kt << 5;
#pragma unroll
            for (int cc = 0; cc < 2; ++cc) {
                const int s = cc * 4 + w;
                GLL(Ap + (size_t)(am + s * 16 + srow) * K + k0s + scol,
                    &At[c][s * 512]);
            }
#pragma unroll
            for (int cc = 0; cc < 2; ++cc) {
                const int s = cc * 4 + w;
                GLL(W + (size_t)(bn + s * 16 + srow) * K + k0s + scol,
                    &Bt[c][s * 512]);
            }
        } else {
            const int k0s = kt << 6;
#pragma unroll
            for (int ks = 0; ks < 2; ++ks)
                GLL(Ap + (size_t)(am + w * 16 + srow) * K + k0s + ks * 32 + scol,
                    &At[c][ks * 2048 + w * 512]);
#pragma unroll
            for (int ks = 0; ks < 2; ++ks)
#pragma unroll
                for (int cc = 0; cc < 2; ++cc) {
                    const int s = cc * 4 + w;
                    GLL(W + (size_t)(bn + s * 16 + srow) * K + k0s + ks * 32 + scol,
                        &Bt[c][ks * 4096 + s * 512]);
                }
        }
    };

    // ---- prologue: stage K-steps 0 and 1 ----
    stage(0, 0);
    stage(1, 1);
    if constexpr (TM == 128) asm volatile("s_waitcnt vmcnt(4)" ::: "memory");
    else                     asm volatile("s_waitcnt vmcnt(6)" ::: "memory");
    __builtin_amdgcn_s_barrier();
    __builtin_amdgcn_sched_barrier(0);

    int c0 = 0;                          // kt % 3 ring counter
    for (int kt = 0; kt < niter; ++kt) {
        const bool pre = (kt + 2 < niter);   // uniform

        // ---- issue prefetch of K-step kt+2 ----
        if (pre) {
            int cn = c0 + 2; if (cn >= 3) cn -= 3;
            stage(kt + 2, cn);
        }
        __builtin_amdgcn_sched_barrier(0);

        // ---- compute K-step kt from buf[c0] ----
#pragma unroll
        for (int ks = 0; ks < NKS; ++ks) {
            bf16x8 af[IM], bfr[4];
#pragma unroll
            for (int i = 0; i < IM; ++i)
                af[i] = *(const bf16x8*)(
                    &At[c0][ks * (TM * 32) + (wm + i * 16 + qi) * 32 + g * 8]);
#pragma unroll
            for (int j2 = 0; j2 < 4; ++j2)
                bfr[j2] = *(const bf16x8*)(
                    &Bt[c0][ks * 4096 + (wn + j2 * 16 + qi) * 32 + g * 8]);
#pragma unroll
            for (int i = 0; i < IM; ++i)
#pragma unroll
                for (int j2 = 0; j2 < 4; ++j2)
                    acc[i][j2] = __builtin_amdgcn_mfma_f32_16x16x32_bf16(
                        af[i], bfr[j2], acc[i][j2], 0, 0, 0);
        }

        // ---- tail: counted wait (kt+1's loads landed), one barrier ----
        if (pre) {
            if constexpr (TM == 128)
                asm volatile("s_waitcnt vmcnt(4)" ::: "memory");
            else
                asm volatile("s_waitcnt vmcnt(6)" ::: "memory");
        } else {
            asm volatile("s_waitcnt vmcnt(0)" ::: "memory");
        }
        __builtin_amdgcn_s_barrier();
        __builtin_amdgcn_sched_barrier(0);
        if (++c0 == 3) c0 = 0;
    }

    // C-layout: col(n) = lane&15, row(m) = (lane>>4)*4 + r
    const float* bp = FUSED ? (bn < 1024 ? b1 : (bn < 2048 ? b2 : b3)) : b1;
#pragma unroll
    for (int j2 = 0; j2 < 4; ++j2) {
        const int n = bn + wn + j2 * 16 + qi;
        const int nl = n & 1023;
        const float bv = bp[nl];
#pragma unroll
        for (int i = 0; i < IM; ++i) {
            if (EPI == 1 && TRV && bn >= N - 1024) {
                // transposed V store: [bh][dk][s], 4 consecutive s per lane
                const int which = bn >> 10;
                const int h = nl >> 6, dk = nl & 63;
                const int m0 = bm + wm + i * 16 + g * 4;
                const int bb = m0 >> 11, s0 = m0 & 2047;
                u16x4 pv;
#pragma unroll
                for (int r = 0; r < 4; ++r) pv[r] = f2b(acc[i][j2][r] + bv);
                *(u16x4*)(C + (size_t)which * 4194304 +
                          (((size_t)((bb << 4) + h)) * 64 + dk) * 2048 + s0) = pv;
            } else {
#pragma unroll
                for (int r = 0; r < 4; ++r) {
                    const int m = bm + wm + i * 16 + g * 4 + r;
                    float v = acc[i][j2][r] + bv;
                    if (EPI == 2) {
                        v += RF32 ? ((const float*)Rv)[(size_t)m * N + n]
                                  : b2f(((const ushort_t*)Rv)[(size_t)m * N + n]);
                    }
                    if (EPI == 3) v = v > 0.f ? v : 0.f;
                    if (EPI == 1) {
                        const int which = FUSED ? (bn >> 10) : 0;
                        if (QSC && which == 0)
                            v *= 0.18033688011112042f;   // log2(e)/8
                        const int bb = m >> 11, s = m & 2047;    // S = 2048
                        const int h = nl >> 6, dk = nl & 63;
                        const size_t dst = (size_t)which * 4194304 +
                            (((size_t)((bb << 4) + h)) * 2048 + s) * 64 + dk;
                        C[dst] = f2b(v);
                    } else {
                        ushort_t* Cp = SPLITC ? (m < 2048 ? C : C2) : C;
                        const int mr = SPLITC ? (m & 2047) : m;
                        Cp[(size_t)mr * N + n] = f2b(v);
                    }
                }
            }
        }
    }
}

// ---------------------------------------------------------------------------
// Flash attention v8. Q (pre-scaled by log2e/8), K: bf16 [B*H, S, 64];
// V: TRANSPOSED bf16 [B*H, 64, S]; O: bf16 [B*S, 1024].
// 64 q-rows/block (4 waves x 16). KVBLK=64: each barrier step processes TWO
// 32-key subtiles (sub-layouts identical to v7). Ring of 3 slots; prefetch
// step s+2 (4 GLLs); counted vmcnt(4) tail; ONE barrier per 64 keys.
// ntiles is always even -> nsteps = ntiles/2 exactly, no tail case.
// ---------------------------------------------------------------------------
template <bool CAUSAL>
__global__ __launch_bounds__(256) void flash_attn(
    const ushort_t* __restrict__ Q, const ushort_t* __restrict__ K,
    const ushort_t* __restrict__ V, ushort_t* __restrict__ O, int S)
{
    __shared__ __align__(16) ushort_t Kt[3][2][2048];
    __shared__ __align__(16) ushort_t Vt[3][2][2048];
    __shared__ __align__(16) ushort_t Pl[2048];

    const int tid = threadIdx.x, lane = tid & 63, w = tid >> 6;
    const int g = lane >> 4, qi = lane & 15;
    const int q2 = (qi >> 1) & 3;            // P-tile swizzle key
    const int bh = blockIdx.x;
    const int y = blockIdx.y;
    const int qb = CAUSAL ? ((y & 8) ? ((y & 16) ? 55 - y : 23 - y) : y) : y;
    const size_t base = (size_t)bh * S * 64;
    const int q0 = qb << 6;
    const int qw = q0 + w * 16;

    // K GLL source (wave w fills a Kt subtile's elems [w*512, w*512+512)):
    const int krow2 = ((w & 1) << 4) + (lane >> 2);
    const int kcol2 = ((w >> 1) << 5) + ((lane & 3) << 3);
    const ushort_t* Kp = K + base + (size_t)krow2 * 64 + kcol2;
    // V GLL source (V^T global [bh][d][s]; wave w fills Vt rows w*16..w*16+15):
    const ushort_t* Vp = V + base + (size_t)(w * 16 + (lane >> 2)) * 2048 +
                         ((lane & 3) << 3);

    bf16x8 qf0 = *(const bf16x8*)(Q + base + (size_t)(qw + qi) * 64 + g * 8);
    bf16x8 qf1 = *(const bf16x8*)(Q + base + (size_t)(qw + qi) * 64 + 32 + g * 8);
    // pin: forces the Q-load wait HERE (before any GLL issues) so the manual
    // vmcnt counts below only ever see GLLs
    asm volatile("" :: "v"(qf0), "v"(qf1));

    f32x4 oacc[4] = {};
    float lsum = 0.f;                        // per-lane partial of sum(p)

    // ntiles (32-key) is always even: causal 2qb+2, cross 64.
    const int nsteps = (CAUSAL ? ((q0 >> 5) + 2) : (S >> 5)) >> 1;   // >= 1

    // stage 64-key step st into ring slot c (4 GLLs/wave)
    auto stageKV = [&](int st, int c) {
        const int kn = st << 6;
        GLL(Kp + (size_t)kn * 64, &Kt[c][0][w * 512]);
        GLL(Kp + (size_t)(kn + 32) * 64, &Kt[c][1][w * 512]);
        GLL(Vp + kn, &Vt[c][0][w * 512]);
        GLL(Vp + kn + 32, &Vt[c][1][w * 512]);
    };

    // ---- prologue: stage steps 0 and 1 (step 1 may be unused; in-bounds) ----
    stageKV(0, 0);
    stageKV(1, 1);
    asm volatile("s_waitcnt vmcnt(4)" ::: "memory");   // step 0 landed
    __builtin_amdgcn_s_barrier();
    __builtin_amdgcn_sched_barrier(0);

    int c0 = 0;                              // step % 3 ring counter
    for (int s = 0; s < nsteps; ++s) {
        const bool pre = (s + 2 < nsteps);   // uniform across block

        // ---- issue prefetch of step s+2 ----
        if (pre) {
            int cn = c0 + 2; if (cn >= 3) cn -= 3;
            stageKV(s + 2, cn);
        }
        __builtin_amdgcn_sched_barrier(0);

        // ---- two 32-key subtiles ----
#pragma unroll
        for (int sub = 0; sub < 2; ++sub) {
            const int kk = (s << 6) + (sub << 5);

            f32x4 st2[2] = {};
            __builtin_amdgcn_s_setprio(1);
#pragma unroll
            for (int tt = 0; tt < 2; ++tt) {
                bf16x8 kf0 = *(const bf16x8*)(&Kt[c0][sub][(tt * 16 + qi) * 32 + g * 8]);
                bf16x8 kf1 = *(const bf16x8*)(&Kt[c0][sub][1024 + (tt * 16 + qi) * 32 + g * 8]);
                st2[tt] = __builtin_amdgcn_mfma_f32_16x16x32_bf16(kf0, qf0, st2[tt], 0, 0, 0);
                st2[tt] = __builtin_amdgcn_mfma_f32_16x16x32_bf16(kf1, qf1, st2[tt], 0, 0, 0);
            }
            __builtin_amdgcn_s_setprio(0);

            if (CAUSAL && (kk + 31 > qw)) {
#pragma unroll
                for (int tt = 0; tt < 2; ++tt)
#pragma unroll
                    for (int r = 0; r < 4; ++r)
                        if (kk + tt * 16 + g * 4 + r > qw + qi) st2[tt][r] = -1e30f;
            }

            // no-max softmax: p = exp2(st) (Q pre-scaled by log2e/8)
            float p[2][4];
#pragma unroll
            for (int tt = 0; tt < 2; ++tt)
#pragma unroll
                for (int r = 0; r < 4; ++r) {
                    p[tt][r] = EXP2(st2[tt][r]);
                    lsum += p[tt][r];
                }

            // P round trip (wave-private region, swizzled, conflict-free b64)
            ushort_t* pb = Pl + w * 512;
#pragma unroll
            for (int tt = 0; tt < 2; ++tt) {
                unsigned lo, hi;
                asm("v_cvt_pk_bf16_f32 %0, %1, %2" : "=v"(lo) : "v"(p[tt][0]), "v"(p[tt][1]));
                asm("v_cvt_pk_bf16_f32 %0, %1, %2" : "=v"(hi) : "v"(p[tt][2]), "v"(p[tt][3]));
                const int swc = (tt * 2 + (g >> 1)) ^ q2;
                uint2 pw; pw.x = lo; pw.y = hi;
                *(uint2*)(pb + qi * 32 + swc * 8 + (g & 1) * 4) = pw;
            }
            asm volatile("s_waitcnt lgkmcnt(0)" ::: "memory");
            __builtin_amdgcn_sched_barrier(0);
            bf16x8 pf = *(const bf16x8*)(pb + qi * 32 + ((g ^ q2) << 3));

            // PV from this subtile
            __builtin_amdgcn_s_setprio(1);
#pragma unroll
            for (int dt = 0; dt < 4; ++dt) {
                bf16x8 vf = *(const bf16x8*)(&Vt[c0][sub][(dt * 16 + qi) * 32 + g * 8]);
                oacc[dt] = __builtin_amdgcn_mfma_f32_16x16x32_bf16(pf, vf, oacc[dt], 0, 0, 0);
            }
            __builtin_amdgcn_s_setprio(0);
        }

        // ---- tail: counted wait (step s+1's loads landed), one barrier ----
        if (pre) {
            asm volatile("s_waitcnt vmcnt(4)" ::: "memory");
        } else {
            asm volatile("s_waitcnt vmcnt(0)" ::: "memory");
        }
        __builtin_amdgcn_s_barrier();
        __builtin_amdgcn_sched_barrier(0);
        if (++c0 == 3) c0 = 0;
    }

    lsum += __shfl_xor(lsum, 16);
    lsum += __shfl_xor(lsum, 32);
    float lv[4];
#pragma unroll
    for (int r = 0; r < 4; ++r) lv[r] = 1.f / __shfl(lsum, g * 4 + r, 16);

    const int b = bh >> 4, h = bh & 15;
#pragma unroll
    for (int dt = 0; dt < 4; ++dt)
#pragma unroll
        for (int r = 0; r < 4; ++r) {
            const int row = b * S + qw + g * 4 + r;
            const int col = (h << 6) + dt * 16 + qi;
            O[(size_t)row * 1024 + col] = f2b(oacc[dt][r] * lv[r]);
        }
}

// ---------------------------------------------------------------------------
// LayerNorm D=1024. X bf16 ws; gamma/beta fp32; OUT fp32 (final) or bf16.
// ---------------------------------------------------------------------------
template <bool OUTF32>
__global__ __launch_bounds__(256) void ln_kernel(
    const ushort_t* __restrict__ X, const float* __restrict__ gam,
    const float* __restrict__ bet, void* __restrict__ Yv)
{
    const int row = blockIdx.x, tid = threadIdx.x;
    const int lane = tid & 63, w = tid >> 6;
    const size_t off = (size_t)row * 1024 + tid * 4;

    u16x4 xv = *(const u16x4*)(X + off);
    float f[4];
#pragma unroll
    for (int i = 0; i < 4; ++i) f[i] = b2f(xv[i]);

    float s = f[0] + f[1] + f[2] + f[3];
    float sq = f[0] * f[0] + f[1] * f[1] + f[2] * f[2] + f[3] * f[3];
#pragma unroll
    for (int o = 32; o; o >>= 1) {
        s  += __shfl_xor(s, o);
        sq += __shfl_xor(sq, o);
    }
    __shared__ float red[8];
    if (lane == 0) { red[w] = s; red[4 + w] = sq; }
    __syncthreads();
    s  = red[0] + red[1] + red[2] + red[3];
    sq = red[4] + red[5] + red[6] + red[7];

    const float mu = s * (1.f / 1024.f);
    const float var = sq * (1.f / 1024.f) - mu * mu;
    const float rs = rsqrtf(var + 1e-5f);

    const float4 gv = *(const float4*)(gam + tid * 4);
    const float4 bv = *(const float4*)(bet + tid * 4);
    float y0 = (f[0] - mu) * rs * gv.x + bv.x;
    float y1 = (f[1] - mu) * rs * gv.y + bv.y;
    float y2 = (f[2] - mu) * rs * gv.z + bv.z;
    float y3 = (f[3] - mu) * rs * gv.w + bv.w;

    if (OUTF32) {
        float4 yv; yv.x = y0; yv.y = y1; yv.z = y2; yv.w = y3;
        *(float4*)((float*)Yv + off) = yv;
    } else {
        u16x4 yv;
        yv[0] = f2b(y0); yv[1] = f2b(y1); yv[2] = f2b(y2); yv[3] = f2b(y3);
        *(u16x4*)((ushort_t*)Yv + off) = yv;
    }
}

// ---------------------------------------------------------------------------
extern "C" void kernel_launch(void* const* d_in, const int* in_sizes, int n_in,
                              void* d_out, int out_size, void* d_ws, size_t ws_size,
                              hipStream_t stream)
{
    const float* x   = (const float*)d_in[0];
    const float* enc = (const float*)d_in[1];
    const float* Wq1 = (const float*)d_in[4];
    const float* bq1 = (const float*)d_in[5];
    const float* Wk1 = (const float*)d_in[6];
    const float* bk1 = (const float*)d_in[7];
    const float* Wv1 = (const float*)d_in[8];
    const float* bv1 = (const float*)d_in[9];
    const float* Wo1 = (const float*)d_in[10];
    const float* bo1 = (const float*)d_in[11];
    const float* Wq2 = (const float*)d_in[12];
    const float* bq2 = (const float*)d_in[13];
    const float* Wk2 = (const float*)d_in[14];
    const float* bk2 = (const float*)d_in[15];
    const float* Wv2 = (const float*)d_in[16];
    const float* bv2 = (const float*)d_in[17];
    const float* Wo2 = (const float*)d_in[18];
    const float* bo2 = (const float*)d_in[19];
    const float* Wf1 = (const float*)d_in[20];
    const float* bf1 = (const float*)d_in[21];
    const float* Wf2 = (const float*)d_in[22];
    const float* bf2 = (const float*)d_in[23];
    const float* gm1 = (const float*)d_in[24];
    const float* be1 = (const float*)d_in[25];
    const float* gm2 = (const float*)d_in[26];
    const float* be2 = (const float*)d_in[27];
    const float* gm3 = (const float*)d_in[28];
    const float* be3 = (const float*)d_in[29];

    float*    out = (float*)d_out;
    ushort_t* ws  = (ushort_t*)d_ws;
    ushort_t* F2  = (ushort_t*)d_out;   // 16 MB bf16 scratch until final LN

    const size_t E = (size_t)4096 * 1024;
    ushort_t* P0 = ws;
    ushort_t* P1 = ws + 1 * E;
    ushort_t* P2 = ws + 2 * E;
    ushort_t* P3 = ws + 3 * E;
    ushort_t* P4 = ws + 4 * E;
    ushort_t* Wb = ws + 5 * E;          // 16M bf16 weights (32 MB)

    const size_t M1 = 1048576;
    ushort_t* Wb_qkv1 = Wb;              // q1,k1,v1 contiguous
    ushort_t* Wb_o1   = Wb + 3 * M1;
    ushort_t* Wb_q2   = Wb + 4 * M1;
    ushort_t* Wb_kv2  = Wb + 5 * M1;     // k2,v2 contiguous
    ushort_t* Wb_o2   = Wb + 7 * M1;
    ushort_t* Wb_f1   = Wb + 8 * M1;
    ushort_t* Wb_f2   = Wb + 12 * M1;

    const dim3 blk(256);
    const dim3 gA(32, 32);               // x = bh, y = qb (balanced for causal)

    // ---- convert x, enc, all weights to bf16 ----
    conv_all<<<12288, blk, 0, stream>>>(x, enc, Wq1, Wk1, Wv1, Wo1, Wq2, Wk2,
                                        Wv2, Wo2, Wf1, Wf2, P3, P4, Wb);

    // ---- self attention ----
    // QKV fused: Q->P0 (pre-scaled), K->P1, V->P2 (V TRANSPOSED [bh][dk][s])
    gemm_bt<1, 128, false, true, false, false, true, true><<<dim3(24, 32), blk, 0, stream>>>(
        P3, nullptr, Wb_qkv1, bq1, bk1, bv1, nullptr, P0, nullptr, 4096, 3072, 1024);
    flash_attn<true><<<gA, blk, 0, stream>>>(P0, P1, P2, P3, 2048);
    gemm_bt<2, 64, true, false, false, false, false, false><<<dim3(8, 64), blk, 0, stream>>>(
        P3, nullptr, Wb_o1, bo1, bo1, bo1, x, P0, nullptr, 4096, 1024, 1024);
    ln_kernel<false><<<4096, blk, 0, stream>>>(P0, gm1, be1, P1);   // X1 = P1

    // ---- cross attention ----
    // cross-Q (pre-scaled) -> P0
    gemm_bt<1, 64, false, false, false, false, false, true><<<dim3(8, 64), blk, 0, stream>>>(
        P1, nullptr, Wb_q2, bq2, bq2, bq2, nullptr, P0, nullptr, 4096, 1024, 1024);
    // cross-KV fused: K->P2, V->P3 (V TRANSPOSED); QSC=false (which 0 is K!)
    gemm_bt<1, 128, false, true, false, false, true, false><<<dim3(16, 32), blk, 0, stream>>>(
        P4, nullptr, Wb_kv2, bk2, bv2, bv2, nullptr, P2, nullptr, 4096, 2048, 1024);
    flash_attn<false><<<gA, blk, 0, stream>>>(P0, P2, P3, P4, 2048);
    gemm_bt<2, 64, false, false, false, false, false, false><<<dim3(8, 64), blk, 0, stream>>>(
        P4, nullptr, Wb_o2, bo2, bo2, bo2, P1, P0, nullptr, 4096, 1024, 1024);
    ln_kernel<false><<<4096, blk, 0, stream>>>(P0, gm2, be2, P2);   // X2 = P2

    // ---- FFN ----
    gemm_bt<3, 128, false, false, false, true, false, false><<<dim3(32, 32), blk, 0, stream>>>(
        P2, nullptr, Wb_f1, bf1, bf1, bf1, nullptr, P0, F2, 4096, 4096, 1024);
    gemm_bt<2, 64, false, false, true, false, false, false><<<dim3(8, 64), blk, 0, stream>>>(
        P0, F2, Wb_f2, bf2, bf2, bf2, P2, P3, nullptr, 4096, 1024, 4096);
    ln_kernel<true><<<4096, blk, 0, stream>>>(P3, gm3, be3, out);
}

// Round 11
// 527.112 us; speedup vs baseline: 1.0440x; 1.0440x over previous
//
#include <hip/hip_runtime.h>

// ---------------------------------------------------------------------------
// DecoderLayer (B=2, S=T=2048, D=1024, H=16, DK=64, DF=4096).
// fp32 interface; internal bf16 MFMA. ws = 72 MB:
//   P0..P4 : 5 x 8 MB activation slots
//   Wb     : 32 MB bf16 weights (converted once per launch by conv_all)
// d_out doubles as 16 MB bf16 scratch (F2) until the final LN.
// GEMMs v9: 3-buffer LDS ring, counted vmcnt, ONE barrier per K-step.
//   TM=128: BK=32 (48 KB ring).  TM=64: BK=64 (72 KB ring).
// flash_attn v9: KVBLK=64 with RING-2 (36 KB LDS -> 4-block/CU capacity =
//   grid residency; v8's ring-3 at 53 KB dropped to 3 blocks/CU and
//   regressed). One barrier per 64 keys; prefetch issued a full step ahead
//   (L2-resident KV -> tail drain ~0). No-max softmax p = exp2(st).
// ---------------------------------------------------------------------------

typedef __bf16 bf16_t;
typedef bf16_t  bf16x8 __attribute__((ext_vector_type(8)));
typedef float   f32x4  __attribute__((ext_vector_type(4)));
typedef unsigned short ushort_t;
typedef ushort_t u16x8 __attribute__((ext_vector_type(8)));
typedef ushort_t u16x4 __attribute__((ext_vector_type(4)));

__device__ __forceinline__ float b2f(ushort_t u) {
    union { unsigned u; float f; } x; x.u = ((unsigned)u) << 16; return x.f;
}
__device__ __forceinline__ ushort_t f2b(float f) {     // RNE
    union { float f; unsigned u; } x; x.f = f;
    unsigned r = x.u + 0x7fffu + ((x.u >> 16) & 1u);
    return (ushort_t)(r >> 16);
}
__device__ __forceinline__ unsigned pk2(float lo, float hi) {
    union { float f; unsigned u; } a, b; a.f = lo; b.f = hi;
    return (b.u & 0xffff0000u) | (a.u >> 16);
}

#if __has_builtin(__builtin_amdgcn_exp2f)
#define EXP2(x) __builtin_amdgcn_exp2f(x)
#else
#define EXP2(x) exp2f(x)
#endif

// global -> LDS direct, 16B per lane (LDS dest = wave-uniform base + lane*16)
#define GLL(gp, lp)                                                            \
    __builtin_amdgcn_global_load_lds(                                          \
        (const __attribute__((address_space(1))) void*)(gp),                   \
        (__attribute__((address_space(3))) void*)(lp), 16, 0, 0)

// ---------------------------------------------------------------------------
// conv_all: fp32 -> bf16 (truncation). 12288 blocks x 256 thr x 8 elems.
// ---------------------------------------------------------------------------
__global__ __launch_bounds__(256) void conv_all(
    const float* __restrict__ x,   const float* __restrict__ enc,
    const float* __restrict__ w0, const float* __restrict__ w1,
    const float* __restrict__ w2, const float* __restrict__ w3,
    const float* __restrict__ w4, const float* __restrict__ w5,
    const float* __restrict__ w6, const float* __restrict__ w7,
    const float* __restrict__ wf1, const float* __restrict__ wf2,
    ushort_t* __restrict__ Xb, ushort_t* __restrict__ Eb,
    ushort_t* __restrict__ Wb)
{
    const int b = blockIdx.x;
    const float* src;
    ushort_t* dst;
    size_t blk;
    if (b < 2048)      { src = x;   dst = Xb; blk = b; }
    else if (b < 4096) { src = enc; dst = Eb; blk = b - 2048; }
    else if (b < 8192) {
        const int i = (b - 4096) >> 9;
        src = (i < 4) ? (i < 2 ? (i == 0 ? w0 : w1) : (i == 2 ? w2 : w3))
                      : (i < 6 ? (i == 4 ? w4 : w5) : (i == 6 ? w6 : w7));
        dst = Wb + (size_t)i * 1048576;
        blk = (b - 4096) & 511;
    }
    else if (b < 10240) { src = wf1; dst = Wb + (size_t)8  * 1048576; blk = b - 8192; }
    else                { src = wf2; dst = Wb + (size_t)12 * 1048576; blk = b - 10240; }

    const size_t e = blk * 2048 + (size_t)threadIdx.x * 8;
    const float4 a = *(const float4*)(src + e);
    const float4 c = *(const float4*)(src + e + 4);
    uint4 r;
    r.x = pk2(a.x, a.y); r.y = pk2(a.z, a.w);
    r.z = pk2(c.x, c.y); r.w = pk2(c.z, c.w);
    *(uint4*)(dst + e) = r;
}

// ---------------------------------------------------------------------------
// GEMM v9: A[M,K] @ W[N,K]^T + bias (all bf16). TM x 128 tile.
// TM=128: BK=32, ring3, vmcnt(4).  TM=64: BK=64, ring3, vmcnt(6).
// One barrier per K-step. XCD-aware block remap.
// EPI=1: permute-store -> [B,H,S,64] slot (+ (bn>>10)*4M if FUSED)
//   TRV: last 1024-col region stores V TRANSPOSED [B,H,64,S].
//   QSC: which==0 region (the Q projection) is pre-scaled by log2(e)/8.
// EPI=2: + residual (RF32: fp32 residual)    EPI=3: ReLU
// ---------------------------------------------------------------------------
template <int EPI, int TM, bool RF32, bool FUSED, bool SPLITA, bool SPLITC,
          bool TRV, bool QSC>
__global__ __launch_bounds__(256) void gemm_bt(
    const ushort_t* __restrict__ A, const ushort_t* __restrict__ A2,
    const ushort_t* __restrict__ W,
    const float* __restrict__ b1, const float* __restrict__ b2,
    const float* __restrict__ b3,
    const void* __restrict__ Rv,
    ushort_t* __restrict__ C, ushort_t* __restrict__ C2,
    int M, int N, int K)
{
    constexpr int IM = TM / 32;                  // acc rows per wave
    constexpr int NKS = (TM == 128) ? 1 : 2;     // 32-wide K-subtiles per step
    constexpr int ASLOT = NKS * TM * 32;
    constexpr int BSLOT = NKS * 128 * 32;
    __shared__ __align__(16) ushort_t At[3][ASLOT];
    __shared__ __align__(16) ushort_t Bt[3][BSLOT];

    const int tid  = threadIdx.x;
    const int lane = tid & 63, w = tid >> 6;
    const int g = lane >> 4, qi = lane & 15;

    // XCD-aware remap (bijective; nbm is a multiple of 8 for all our grids)
    const int nbn = gridDim.x, nbm = gridDim.y;
    const int lin = blockIdx.x + nbn * blockIdx.y;
    const int xcd = lin & 7, j = lin >> 3;
    const int bpx = nbm >> 3;                   // bm-blocks per xcd
    const int bmb = xcd * bpx + (j & (bpx - 1));
    const int bnb = j / bpx;
    const int bm = bmb * TM, bn = bnb * 128;

    const int wm = (w >> 1) * (TM / 2), wn = (w & 1) * 64;

    const ushort_t* Ap = SPLITA ? ((bm < 2048) ? A : A2) : A;
    const int       am = SPLITA ? (bm & 2047) : bm;

    const int srow = lane >> 2;          // row within a 16-row segment
    const int scol = (lane & 3) * 8;     // bf16 col within 32

    f32x4 acc[IM][4] = {};

    const int niter = (TM == 128) ? (K >> 5) : (K >> 6);   // >= 16 always

    // stage K-step kt into ring buffer c
    auto stage = [&](int kt, int c) {
        if constexpr (TM == 128) {
            const int k0s = kt << 5;
#pragma unroll
            for (int cc = 0; cc < 2; ++cc) {
                const int s = cc * 4 + w;
                GLL(Ap + (size_t)(am + s * 16 + srow) * K + k0s + scol,
                    &At[c][s * 512]);
            }
#pragma unroll
            for (int cc = 0; cc < 2; ++cc) {
                const int s = cc * 4 + w;
                GLL(W + (size_t)(bn + s * 16 + srow) * K + k0s + scol,
                    &Bt[c][s * 512]);
            }
        } else {
            const int k0s = kt << 6;
#pragma unroll
            for (int ks = 0; ks < 2; ++ks)
                GLL(Ap + (size_t)(am + w * 16 + srow) * K + k0s + ks * 32 + scol,
                    &At[c][ks * 2048 + w * 512]);
#pragma unroll
            for (int ks = 0; ks < 2; ++ks)
#pragma unroll
                for (int cc = 0; cc < 2; ++cc) {
                    const int s = cc * 4 + w;
                    GLL(W + (size_t)(bn + s * 16 + srow) * K + k0s + ks * 32 + scol,
                        &Bt[c][ks * 4096 + s * 512]);
                }
        }
    };

    // ---- prologue: stage K-steps 0 and 1 ----
    stage(0, 0);
    stage(1, 1);
    if constexpr (TM == 128) asm volatile("s_waitcnt vmcnt(4)" ::: "memory");
    else                     asm volatile("s_waitcnt vmcnt(6)" ::: "memory");
    __builtin_amdgcn_s_barrier();
    __builtin_amdgcn_sched_barrier(0);

    int c0 = 0;                          // kt % 3 ring counter
    for (int kt = 0; kt < niter; ++kt) {
        const bool pre = (kt + 2 < niter);   // uniform

        // ---- issue prefetch of K-step kt+2 ----
        if (pre) {
            int cn = c0 + 2; if (cn >= 3) cn -= 3;
            stage(kt + 2, cn);
        }
        __builtin_amdgcn_sched_barrier(0);

        // ---- compute K-step kt from buf[c0] ----
#pragma unroll
        for (int ks = 0; ks < NKS; ++ks) {
            bf16x8 af[IM], bfr[4];
#pragma unroll
            for (int i = 0; i < IM; ++i)
                af[i] = *(const bf16x8*)(
                    &At[c0][ks * (TM * 32) + (wm + i * 16 + qi) * 32 + g * 8]);
#pragma unroll
            for (int j2 = 0; j2 < 4; ++j2)
                bfr[j2] = *(const bf16x8*)(
                    &Bt[c0][ks * 4096 + (wn + j2 * 16 + qi) * 32 + g * 8]);
#pragma unroll
            for (int i = 0; i < IM; ++i)
#pragma unroll
                for (int j2 = 0; j2 < 4; ++j2)
                    acc[i][j2] = __builtin_amdgcn_mfma_f32_16x16x32_bf16(
                        af[i], bfr[j2], acc[i][j2], 0, 0, 0);
        }

        // ---- tail: counted wait (kt+1's loads landed), one barrier ----
        if (pre) {
            if constexpr (TM == 128)
                asm volatile("s_waitcnt vmcnt(4)" ::: "memory");
            else
                asm volatile("s_waitcnt vmcnt(6)" ::: "memory");
        } else {
            asm volatile("s_waitcnt vmcnt(0)" ::: "memory");
        }
        __builtin_amdgcn_s_barrier();
        __builtin_amdgcn_sched_barrier(0);
        if (++c0 == 3) c0 = 0;
    }

    // C-layout: col(n) = lane&15, row(m) = (lane>>4)*4 + r
    const float* bp = FUSED ? (bn < 1024 ? b1 : (bn < 2048 ? b2 : b3)) : b1;
#pragma unroll
    for (int j2 = 0; j2 < 4; ++j2) {
        const int n = bn + wn + j2 * 16 + qi;
        const int nl = n & 1023;
        const float bv = bp[nl];
#pragma unroll
        for (int i = 0; i < IM; ++i) {
            if (EPI == 1 && TRV && bn >= N - 1024) {
                // transposed V store: [bh][dk][s], 4 consecutive s per lane
                const int which = bn >> 10;
                const int h = nl >> 6, dk = nl & 63;
                const int m0 = bm + wm + i * 16 + g * 4;
                const int bb = m0 >> 11, s0 = m0 & 2047;
                u16x4 pv;
#pragma unroll
                for (int r = 0; r < 4; ++r) pv[r] = f2b(acc[i][j2][r] + bv);
                *(u16x4*)(C + (size_t)which * 4194304 +
                          (((size_t)((bb << 4) + h)) * 64 + dk) * 2048 + s0) = pv;
            } else {
#pragma unroll
                for (int r = 0; r < 4; ++r) {
                    const int m = bm + wm + i * 16 + g * 4 + r;
                    float v = acc[i][j2][r] + bv;
                    if (EPI == 2) {
                        v += RF32 ? ((const float*)Rv)[(size_t)m * N + n]
                                  : b2f(((const ushort_t*)Rv)[(size_t)m * N + n]);
                    }
                    if (EPI == 3) v = v > 0.f ? v : 0.f;
                    if (EPI == 1) {
                        const int which = FUSED ? (bn >> 10) : 0;
                        if (QSC && which == 0)
                            v *= 0.18033688011112042f;   // log2(e)/8
                        const int bb = m >> 11, s = m & 2047;    // S = 2048
                        const int h = nl >> 6, dk = nl & 63;
                        const size_t dst = (size_t)which * 4194304 +
                            (((size_t)((bb << 4) + h)) * 2048 + s) * 64 + dk;
                        C[dst] = f2b(v);
                    } else {
                        ushort_t* Cp = SPLITC ? (m < 2048 ? C : C2) : C;
                        const int mr = SPLITC ? (m & 2047) : m;
                        Cp[(size_t)mr * N + n] = f2b(v);
                    }
                }
            }
        }
    }
}

// ---------------------------------------------------------------------------
// Flash attention v9. Q (pre-scaled by log2e/8), K: bf16 [B*H, S, 64];
// V: TRANSPOSED bf16 [B*H, 64, S]; O: bf16 [B*S, 1024].
// 64 q-rows/block (4 waves x 16). KVBLK=64: two 32-key subtiles per barrier
// step. RING-2 (36 KB LDS -> 4 blocks/CU = grid residency). Prefetch of step
// s+1 issued at top of step s (4 GLLs); tail vmcnt(0) drains loads issued a
// full 64-key compute earlier (L2-resident KV -> ~free). ONE barrier/step.
// Ring-2 hazard: prefetch writes slot (s+1)&1 while compute reads s&1
// (disjoint); slot reuse is protected by the previous step's tail barrier.
// ---------------------------------------------------------------------------
template <bool CAUSAL>
__global__ __launch_bounds__(256) void flash_attn(
    const ushort_t* __restrict__ Q, const ushort_t* __restrict__ K,
    const ushort_t* __restrict__ V, ushort_t* __restrict__ O, int S)
{
    __shared__ __align__(16) ushort_t Kt[2][2][2048];
    __shared__ __align__(16) ushort_t Vt[2][2][2048];
    __shared__ __align__(16) ushort_t Pl[2048];

    const int tid = threadIdx.x, lane = tid & 63, w = tid >> 6;
    const int g = lane >> 4, qi = lane & 15;
    const int q2 = (qi >> 1) & 3;            // P-tile swizzle key
    const int bh = blockIdx.x;
    const int y = blockIdx.y;
    const int qb = CAUSAL ? ((y & 8) ? ((y & 16) ? 55 - y : 23 - y) : y) : y;
    const size_t base = (size_t)bh * S * 64;
    const int q0 = qb << 6;
    const int qw = q0 + w * 16;

    // K GLL source (wave w fills a Kt subtile's elems [w*512, w*512+512)):
    const int krow2 = ((w & 1) << 4) + (lane >> 2);
    const int kcol2 = ((w >> 1) << 5) + ((lane & 3) << 3);
    const ushort_t* Kp = K + base + (size_t)krow2 * 64 + kcol2;
    // V GLL source (V^T global [bh][d][s]; wave w fills Vt rows w*16..w*16+15):
    const ushort_t* Vp = V + base + (size_t)(w * 16 + (lane >> 2)) * 2048 +
                         ((lane & 3) << 3);

    bf16x8 qf0 = *(const bf16x8*)(Q + base + (size_t)(qw + qi) * 64 + g * 8);
    bf16x8 qf1 = *(const bf16x8*)(Q + base + (size_t)(qw + qi) * 64 + 32 + g * 8);
    // pin: forces the Q-load wait HERE (before any GLL issues) so the manual
    // vmcnt counts below only ever see GLLs
    asm volatile("" :: "v"(qf0), "v"(qf1));

    f32x4 oacc[4] = {};
    float lsum = 0.f;                        // per-lane partial of sum(p)

    // ntiles (32-key) is always even: causal 2qb+2, cross 64.
    const int nsteps = (CAUSAL ? ((q0 >> 5) + 2) : (S >> 5)) >> 1;   // >= 1

    // stage 64-key step st into ring slot c (4 GLLs/wave)
    auto stageKV = [&](int st, int c) {
        const int kn = st << 6;
        GLL(Kp + (size_t)kn * 64, &Kt[c][0][w * 512]);
        GLL(Kp + (size_t)(kn + 32) * 64, &Kt[c][1][w * 512]);
        GLL(Vp + kn, &Vt[c][0][w * 512]);
        GLL(Vp + kn + 32, &Vt[c][1][w * 512]);
    };

    // ---- prologue: stage step 0 into slot 0 ----
    stageKV(0, 0);
    asm volatile("s_waitcnt vmcnt(0)" ::: "memory");
    __builtin_amdgcn_s_barrier();
    __builtin_amdgcn_sched_barrier(0);

    for (int s = 0; s < nsteps; ++s) {
        const int c0 = s & 1;
        const bool pre = (s + 1 < nsteps);   // uniform across block

        // ---- issue prefetch of step s+1 into slot c0^1 ----
        if (pre) stageKV(s + 1, c0 ^ 1);
        __builtin_amdgcn_sched_barrier(0);

        // ---- two 32-key subtiles ----
#pragma unroll
        for (int sub = 0; sub < 2; ++sub) {
            const int kk = (s << 6) + (sub << 5);

            f32x4 st2[2] = {};
            __builtin_amdgcn_s_setprio(1);
#pragma unroll
            for (int tt = 0; tt < 2; ++tt) {
                bf16x8 kf0 = *(const bf16x8*)(&Kt[c0][sub][(tt * 16 + qi) * 32 + g * 8]);
                bf16x8 kf1 = *(const bf16x8*)(&Kt[c0][sub][1024 + (tt * 16 + qi) * 32 + g * 8]);
                st2[tt] = __builtin_amdgcn_mfma_f32_16x16x32_bf16(kf0, qf0, st2[tt], 0, 0, 0);
                st2[tt] = __builtin_amdgcn_mfma_f32_16x16x32_bf16(kf1, qf1, st2[tt], 0, 0, 0);
            }
            __builtin_amdgcn_s_setprio(0);

            if (CAUSAL && (kk + 31 > qw)) {
#pragma unroll
                for (int tt = 0; tt < 2; ++tt)
#pragma unroll
                    for (int r = 0; r < 4; ++r)
                        if (kk + tt * 16 + g * 4 + r > qw + qi) st2[tt][r] = -1e30f;
            }

            // no-max softmax: p = exp2(st) (Q pre-scaled by log2e/8)
            float p[2][4];
#pragma unroll
            for (int tt = 0; tt < 2; ++tt)
#pragma unroll
                for (int r = 0; r < 4; ++r) {
                    p[tt][r] = EXP2(st2[tt][r]);
                    lsum += p[tt][r];
                }

            // P round trip (wave-private region, swizzled, conflict-free b64)
            ushort_t* pb = Pl + w * 512;
#pragma unroll
            for (int tt = 0; tt < 2; ++tt) {
                unsigned lo, hi;
                asm("v_cvt_pk_bf16_f32 %0, %1, %2" : "=v"(lo) : "v"(p[tt][0]), "v"(p[tt][1]));
                asm("v_cvt_pk_bf16_f32 %0, %1, %2" : "=v"(hi) : "v"(p[tt][2]), "v"(p[tt][3]));
                const int swc = (tt * 2 + (g >> 1)) ^ q2;
                uint2 pw; pw.x = lo; pw.y = hi;
                *(uint2*)(pb + qi * 32 + swc * 8 + (g & 1) * 4) = pw;
            }
            asm volatile("s_waitcnt lgkmcnt(0)" ::: "memory");
            __builtin_amdgcn_sched_barrier(0);
            bf16x8 pf = *(const bf16x8*)(pb + qi * 32 + ((g ^ q2) << 3));

            // PV from this subtile
            __builtin_amdgcn_s_setprio(1);
#pragma unroll
            for (int dt = 0; dt < 4; ++dt) {
                bf16x8 vf = *(const bf16x8*)(&Vt[c0][sub][(dt * 16 + qi) * 32 + g * 8]);
                oacc[dt] = __builtin_amdgcn_mfma_f32_16x16x32_bf16(pf, vf, oacc[dt], 0, 0, 0);
            }
            __builtin_amdgcn_s_setprio(0);
        }

        // ---- tail: drain prefetch (issued a full step earlier), barrier ----
        asm volatile("s_waitcnt vmcnt(0)" ::: "memory");
        __builtin_amdgcn_s_barrier();
        __builtin_amdgcn_sched_barrier(0);
    }

    lsum += __shfl_xor(lsum, 16);
    lsum += __shfl_xor(lsum, 32);
    float lv[4];
#pragma unroll
    for (int r = 0; r < 4; ++r) lv[r] = 1.f / __shfl(lsum, g * 4 + r, 16);

    const int b = bh >> 4, h = bh & 15;
#pragma unroll
    for (int dt = 0; dt < 4; ++dt)
#pragma unroll
        for (int r = 0; r < 4; ++r) {
            const int row = b * S + qw + g * 4 + r;
            const int col = (h << 6) + dt * 16 + qi;
            O[(size_t)row * 1024 + col] = f2b(oacc[dt][r] * lv[r]);
        }
}

// ---------------------------------------------------------------------------
// LayerNorm D=1024. X bf16 ws; gamma/beta fp32; OUT fp32 (final) or bf16.
// ---------------------------------------------------------------------------
template <bool OUTF32>
__global__ __launch_bounds__(256) void ln_kernel(
    const ushort_t* __restrict__ X, const float* __restrict__ gam,
    const float* __restrict__ bet, void* __restrict__ Yv)
{
    const int row = blockIdx.x, tid = threadIdx.x;
    const int lane = tid & 63, w = tid >> 6;
    const size_t off = (size_t)row * 1024 + tid * 4;

    u16x4 xv = *(const u16x4*)(X + off);
    float f[4];
#pragma unroll
    for (int i = 0; i < 4; ++i) f[i] = b2f(xv[i]);

    float s = f[0] + f[1] + f[2] + f[3];
    float sq = f[0] * f[0] + f[1] * f[1] + f[2] * f[2] + f[3] * f[3];
#pragma unroll
    for (int o = 32; o; o >>= 1) {
        s  += __shfl_xor(s, o);
        sq += __shfl_xor(sq, o);
    }
    __shared__ float red[8];
    if (lane == 0) { red[w] = s; red[4 + w] = sq; }
    __syncthreads();
    s  = red[0] + red[1] + red[2] + red[3];
    sq = red[4] + red[5] + red[6] + red[7];

    const float mu = s * (1.f / 1024.f);
    const float var = sq * (1.f / 1024.f) - mu * mu;
    const float rs = rsqrtf(var + 1e-5f);

    const float4 gv = *(const float4*)(gam + tid * 4);
    const float4 bv = *(const float4*)(bet + tid * 4);
    float y0 = (f[0] - mu) * rs * gv.x + bv.x;
    float y1 = (f[1] - mu) * rs * gv.y + bv.y;
    float y2 = (f[2] - mu) * rs * gv.z + bv.z;
    float y3 = (f[3] - mu) * rs * gv.w + bv.w;

    if (OUTF32) {
        float4 yv; yv.x = y0; yv.y = y1; yv.z = y2; yv.w = y3;
        *(float4*)((float*)Yv + off) = yv;
    } else {
        u16x4 yv;
        yv[0] = f2b(y0); yv[1] = f2b(y1); yv[2] = f2b(y2); yv[3] = f2b(y3);
        *(u16x4*)((ushort_t*)Yv + off) = yv;
    }
}

// ---------------------------------------------------------------------------
extern "C" void kernel_launch(void* const* d_in, const int* in_sizes, int n_in,
                              void* d_out, int out_size, void* d_ws, size_t ws_size,
                              hipStream_t stream)
{
    const float* x   = (const float*)d_in[0];
    const float* enc = (const float*)d_in[1];
    const float* Wq1 = (const float*)d_in[4];
    const float* bq1 = (const float*)d_in[5];
    const float* Wk1 = (const float*)d_in[6];
    const float* bk1 = (const float*)d_in[7];
    const float* Wv1 = (const float*)d_in[8];
    const float* bv1 = (const float*)d_in[9];
    const float* Wo1 = (const float*)d_in[10];
    const float* bo1 = (const float*)d_in[11];
    const float* Wq2 = (const float*)d_in[12];
    const float* bq2 = (const float*)d_in[13];
    const float* Wk2 = (const float*)d_in[14];
    const float* bk2 = (const float*)d_in[15];
    const float* Wv2 = (const float*)d_in[16];
    const float* bv2 = (const float*)d_in[17];
    const float* Wo2 = (const float*)d_in[18];
    const float* bo2 = (const float*)d_in[19];
    const float* Wf1 = (const float*)d_in[20];
    const float* bf1 = (const float*)d_in[21];
    const float* Wf2 = (const float*)d_in[22];
    const float* bf2 = (const float*)d_in[23];
    const float* gm1 = (const float*)d_in[24];
    const float* be1 = (const float*)d_in[25];
    const float* gm2 = (const float*)d_in[26];
    const float* be2 = (const float*)d_in[27];
    const float* gm3 = (const float*)d_in[28];
    const float* be3 = (const float*)d_in[29];

    float*    out = (float*)d_out;
    ushort_t* ws  = (ushort_t*)d_ws;
    ushort_t* F2  = (ushort_t*)d_out;   // 16 MB bf16 scratch until final LN

    const size_t E = (size_t)4096 * 1024;
    ushort_t* P0 = ws;
    ushort_t* P1 = ws + 1 * E;
    ushort_t* P2 = ws + 2 * E;
    ushort_t* P3 = ws + 3 * E;
    ushort_t* P4 = ws + 4 * E;
    ushort_t* Wb = ws + 5 * E;          // 16M bf16 weights (32 MB)

    const size_t M1 = 1048576;
    ushort_t* Wb_qkv1 = Wb;              // q1,k1,v1 contiguous
    ushort_t* Wb_o1   = Wb + 3 * M1;
    ushort_t* Wb_q2   = Wb + 4 * M1;
    ushort_t* Wb_kv2  = Wb + 5 * M1;     // k2,v2 contiguous
    ushort_t* Wb_o2   = Wb + 7 * M1;
    ushort_t* Wb_f1   = Wb + 8 * M1;
    ushort_t* Wb_f2   = Wb + 12 * M1;

    const dim3 blk(256);
    const dim3 gA(32, 32);               // x = bh, y = qb (balanced for causal)

    // ---- convert x, enc, all weights to bf16 ----
    conv_all<<<12288, blk, 0, stream>>>(x, enc, Wq1, Wk1, Wv1, Wo1, Wq2, Wk2,
                                        Wv2, Wo2, Wf1, Wf2, P3, P4, Wb);

    // ---- self attention ----
    // QKV fused: Q->P0 (pre-scaled), K->P1, V->P2 (V TRANSPOSED [bh][dk][s])
    gemm_bt<1, 128, false, true, false, false, true, true><<<dim3(24, 32), blk, 0, stream>>>(
        P3, nullptr, Wb_qkv1, bq1, bk1, bv1, nullptr, P0, nullptr, 4096, 3072, 1024);
    flash_attn<true><<<gA, blk, 0, stream>>>(P0, P1, P2, P3, 2048);
    gemm_bt<2, 64, true, false, false, false, false, false><<<dim3(8, 64), blk, 0, stream>>>(
        P3, nullptr, Wb_o1, bo1, bo1, bo1, x, P0, nullptr, 4096, 1024, 1024);
    ln_kernel<false><<<4096, blk, 0, stream>>>(P0, gm1, be1, P1);   // X1 = P1

    // ---- cross attention ----
    // cross-Q (pre-scaled) -> P0
    gemm_bt<1, 64, false, false, false, false, false, true><<<dim3(8, 64), blk, 0, stream>>>(
        P1, nullptr, Wb_q2, bq2, bq2, bq2, nullptr, P0, nullptr, 4096, 1024, 1024);
    // cross-KV fused: K->P2, V->P3 (V TRANSPOSED); QSC=false (which 0 is K!)
    gemm_bt<1, 128, false, true, false, false, true, false><<<dim3(16, 32), blk, 0, stream>>>(
        P4, nullptr, Wb_kv2, bk2, bv2, bv2, nullptr, P2, nullptr, 4096, 2048, 1024);
    flash_attn<false><<<gA, blk, 0, stream>>>(P0, P2, P3, P4, 2048);
    gemm_bt<2, 64, false, false, false, false, false, false><<<dim3(8, 64), blk, 0, stream>>>(
        P4, nullptr, Wb_o2, bo2, bo2, bo2, P1, P0, nullptr, 4096, 1024, 1024);
    ln_kernel<false><<<4096, blk, 0, stream>>>(P0, gm2, be2, P2);   // X2 = P2

    // ---- FFN ----
    gemm_bt<3, 128, false, false, false, true, false, false><<<dim3(32, 32), blk, 0, stream>>>(
        P2, nullptr, Wb_f1, bf1, bf1, bf1, nullptr, P0, F2, 4096, 4096, 1024);
    gemm_bt<2, 64, false, false, true, false, false, false><<<dim3(8, 64), blk, 0, stream>>>(
        P0, F2, Wb_f2, bf2, bf2, bf2, P2, P3, nullptr, 4096, 1024, 4096);
    ln_kernel<true><<<4096, blk, 0, stream>>>(P3, gm3, be3, out);
}

// Round 12
// 522.119 us; speedup vs baseline: 1.0540x; 1.0096x over previous
//
#include <hip/hip_runtime.h>

// ---------------------------------------------------------------------------
// DecoderLayer (B=2, S=T=2048, D=1024, H=16, DK=64, DF=4096).
// fp32 interface; internal bf16 MFMA. ws = 72 MB:
//   P0..P4 : 5 x 8 MB activation slots
//   Wb     : 32 MB bf16 weights (converted once per launch by conv_all)
// d_out doubles as 16 MB bf16 scratch (F2) until the final LN.
// GEMMs v9: 3-buffer LDS ring, counted vmcnt, ONE barrier per K-step.
//   TM=128: BK=32 (48 KB ring).  TM=64: BK=64 (72 KB ring).
// flash_attn v10: KVBLK=64, ring-2 (40 KB LDS -> 4 blocks/CU), MERGED 64-key
//   compute region: QK x8 MFMA -> exp x16 -> P-write x8 -> ONE lgkmcnt ->
//   PV x8 MFMA. Removes one LDS round-trip serialization per step (v9 had
//   two sched_barrier-pinned chains). No-max softmax p = exp2(st).
// ---------------------------------------------------------------------------

typedef __bf16 bf16_t;
typedef bf16_t  bf16x8 __attribute__((ext_vector_type(8)));
typedef float   f32x4  __attribute__((ext_vector_type(4)));
typedef unsigned short ushort_t;
typedef ushort_t u16x8 __attribute__((ext_vector_type(8)));
typedef ushort_t u16x4 __attribute__((ext_vector_type(4)));

__device__ __forceinline__ float b2f(ushort_t u) {
    union { unsigned u; float f; } x; x.u = ((unsigned)u) << 16; return x.f;
}
__device__ __forceinline__ ushort_t f2b(float f) {     // RNE
    union { float f; unsigned u; } x; x.f = f;
    unsigned r = x.u + 0x7fffu + ((x.u >> 16) & 1u);
    return (ushort_t)(r >> 16);
}
__device__ __forceinline__ unsigned pk2(float lo, float hi) {
    union { float f; unsigned u; } a, b; a.f = lo; b.f = hi;
    return (b.u & 0xffff0000u) | (a.u >> 16);
}

#if __has_builtin(__builtin_amdgcn_exp2f)
#define EXP2(x) __builtin_amdgcn_exp2f(x)
#else
#define EXP2(x) exp2f(x)
#endif

// global -> LDS direct, 16B per lane (LDS dest = wave-uniform base + lane*16)
#define GLL(gp, lp)                                                            \
    __builtin_amdgcn_global_load_lds(                                          \
        (const __attribute__((address_space(1))) void*)(gp),                   \
        (__attribute__((address_space(3))) void*)(lp), 16, 0, 0)

// ---------------------------------------------------------------------------
// conv_all: fp32 -> bf16 (truncation). 12288 blocks x 256 thr x 8 elems.
// ---------------------------------------------------------------------------
__global__ __launch_bounds__(256) void conv_all(
    const float* __restrict__ x,   const float* __restrict__ enc,
    const float* __restrict__ w0, const float* __restrict__ w1,
    const float* __restrict__ w2, const float* __restrict__ w3,
    const float* __restrict__ w4, const float* __restrict__ w5,
    const float* __restrict__ w6, const float* __restrict__ w7,
    const float* __restrict__ wf1, const float* __restrict__ wf2,
    ushort_t* __restrict__ Xb, ushort_t* __restrict__ Eb,
    ushort_t* __restrict__ Wb)
{
    const int b = blockIdx.x;
    const float* src;
    ushort_t* dst;
    size_t blk;
    if (b < 2048)      { src = x;   dst = Xb; blk = b; }
    else if (b < 4096) { src = enc; dst = Eb; blk = b - 2048; }
    else if (b < 8192) {
        const int i = (b - 4096) >> 9;
        src = (i < 4) ? (i < 2 ? (i == 0 ? w0 : w1) : (i == 2 ? w2 : w3))
                      : (i < 6 ? (i == 4 ? w4 : w5) : (i == 6 ? w6 : w7));
        dst = Wb + (size_t)i * 1048576;
        blk = (b - 4096) & 511;
    }
    else if (b < 10240) { src = wf1; dst = Wb + (size_t)8  * 1048576; blk = b - 8192; }
    else                { src = wf2; dst = Wb + (size_t)12 * 1048576; blk = b - 10240; }

    const size_t e = blk * 2048 + (size_t)threadIdx.x * 8;
    const float4 a = *(const float4*)(src + e);
    const float4 c = *(const float4*)(src + e + 4);
    uint4 r;
    r.x = pk2(a.x, a.y); r.y = pk2(a.z, a.w);
    r.z = pk2(c.x, c.y); r.w = pk2(c.z, c.w);
    *(uint4*)(dst + e) = r;
}

// ---------------------------------------------------------------------------
// GEMM v9: A[M,K] @ W[N,K]^T + bias (all bf16). TM x 128 tile.
// TM=128: BK=32, ring3, vmcnt(4).  TM=64: BK=64, ring3, vmcnt(6).
// One barrier per K-step. XCD-aware block remap.
// EPI=1: permute-store -> [B,H,S,64] slot (+ (bn>>10)*4M if FUSED)
//   TRV: last 1024-col region stores V TRANSPOSED [B,H,64,S].
//   QSC: which==0 region (the Q projection) is pre-scaled by log2(e)/8.
// EPI=2: + residual (RF32: fp32 residual)    EPI=3: ReLU
// ---------------------------------------------------------------------------
template <int EPI, int TM, bool RF32, bool FUSED, bool SPLITA, bool SPLITC,
          bool TRV, bool QSC>
__global__ __launch_bounds__(256) void gemm_bt(
    const ushort_t* __restrict__ A, const ushort_t* __restrict__ A2,
    const ushort_t* __restrict__ W,
    const float* __restrict__ b1, const float* __restrict__ b2,
    const float* __restrict__ b3,
    const void* __restrict__ Rv,
    ushort_t* __restrict__ C, ushort_t* __restrict__ C2,
    int M, int N, int K)
{
    constexpr int IM = TM / 32;                  // acc rows per wave
    constexpr int NKS = (TM == 128) ? 1 : 2;     // 32-wide K-subtiles per step
    constexpr int ASLOT = NKS * TM * 32;
    constexpr int BSLOT = NKS * 128 * 32;
    __shared__ __align__(16) ushort_t At[3][ASLOT];
    __shared__ __align__(16) ushort_t Bt[3][BSLOT];

    const int tid  = threadIdx.x;
    const int lane = tid & 63, w = tid >> 6;
    const int g = lane >> 4, qi = lane & 15;

    // XCD-aware remap (bijective; nbm is a multiple of 8 for all our grids)
    const int nbn = gridDim.x, nbm = gridDim.y;
    const int lin = blockIdx.x + nbn * blockIdx.y;
    const int xcd = lin & 7, j = lin >> 3;
    const int bpx = nbm >> 3;                   // bm-blocks per xcd
    const int bmb = xcd * bpx + (j & (bpx - 1));
    const int bnb = j / bpx;
    const int bm = bmb * TM, bn = bnb * 128;

    const int wm = (w >> 1) * (TM / 2), wn = (w & 1) * 64;

    const ushort_t* Ap = SPLITA ? ((bm < 2048) ? A : A2) : A;
    const int       am = SPLITA ? (bm & 2047) : bm;

    const int srow = lane >> 2;          // row within a 16-row segment
    const int scol = (lane & 3) * 8;     // bf16 col within 32

    f32x4 acc[IM][4] = {};

    const int niter = (TM == 128) ? (K >> 5) : (K >> 6);   // >= 16 always

    // stage K-step kt into ring buffer c
    auto stage = [&](int kt, int c) {
        if constexpr (TM == 128) {
            const int k0s = kt << 5;
#pragma unroll
            for (int cc = 0; cc < 2; ++cc) {
                const int s = cc * 4 + w;
                GLL(Ap + (size_t)(am + s * 16 + srow) * K + k0s + scol,
                    &At[c][s * 512]);
            }
#pragma unroll
            for (int cc = 0; cc < 2; ++cc) {
                const int s = cc * 4 + w;
                GLL(W + (size_t)(bn + s * 16 + srow) * K + k0s + scol,
                    &Bt[c][s * 512]);
            }
        } else {
            const int k0s = kt << 6;
#pragma unroll
            for (int ks = 0; ks < 2; ++ks)
                GLL(Ap + (size_t)(am + w * 16 + srow) * K + k0s + ks * 32 + scol,
                    &At[c][ks * 2048 + w * 512]);
#pragma unroll
            for (int ks = 0; ks < 2; ++ks)
#pragma unroll
                for (int cc = 0; cc < 2; ++cc) {
                    const int s = cc * 4 + w;
                    GLL(W + (size_t)(bn + s * 16 + srow) * K + k0s + ks * 32 + scol,
                        &Bt[c][ks * 4096 + s * 512]);
                }
        }
    };

    // ---- prologue: stage K-steps 0 and 1 ----
    stage(0, 0);
    stage(1, 1);
    if constexpr (TM == 128) asm volatile("s_waitcnt vmcnt(4)" ::: "memory");
    else                     asm volatile("s_waitcnt vmcnt(6)" ::: "memory");
    __builtin_amdgcn_s_barrier();
    __builtin_amdgcn_sched_barrier(0);

    int c0 = 0;                          // kt % 3 ring counter
    for (int kt = 0; kt < niter; ++kt) {
        const bool pre = (kt + 2 < niter);   // uniform

        // ---- issue prefetch of K-step kt+2 ----
        if (pre) {
            int cn = c0 + 2; if (cn >= 3) cn -= 3;
            stage(kt + 2, cn);
        }
        __builtin_amdgcn_sched_barrier(0);

        // ---- compute K-step kt from buf[c0] ----
#pragma unroll
        for (int ks = 0; ks < NKS; ++ks) {
            bf16x8 af[IM], bfr[4];
#pragma unroll
            for (int i = 0; i < IM; ++i)
                af[i] = *(const bf16x8*)(
                    &At[c0][ks * (TM * 32) + (wm + i * 16 + qi) * 32 + g * 8]);
#pragma unroll
            for (int j2 = 0; j2 < 4; ++j2)
                bfr[j2] = *(const bf16x8*)(
                    &Bt[c0][ks * 4096 + (wn + j2 * 16 + qi) * 32 + g * 8]);
#pragma unroll
            for (int i = 0; i < IM; ++i)
#pragma unroll
                for (int j2 = 0; j2 < 4; ++j2)
                    acc[i][j2] = __builtin_amdgcn_mfma_f32_16x16x32_bf16(
                        af[i], bfr[j2], acc[i][j2], 0, 0, 0);
        }

        // ---- tail: counted wait (kt+1's loads landed), one barrier ----
        if (pre) {
            if constexpr (TM == 128)
                asm volatile("s_waitcnt vmcnt(4)" ::: "memory");
            else
                asm volatile("s_waitcnt vmcnt(6)" ::: "memory");
        } else {
            asm volatile("s_waitcnt vmcnt(0)" ::: "memory");
        }
        __builtin_amdgcn_s_barrier();
        __builtin_amdgcn_sched_barrier(0);
        if (++c0 == 3) c0 = 0;
    }

    // C-layout: col(n) = lane&15, row(m) = (lane>>4)*4 + r
    const float* bp = FUSED ? (bn < 1024 ? b1 : (bn < 2048 ? b2 : b3)) : b1;
#pragma unroll
    for (int j2 = 0; j2 < 4; ++j2) {
        const int n = bn + wn + j2 * 16 + qi;
        const int nl = n & 1023;
        const float bv = bp[nl];
#pragma unroll
        for (int i = 0; i < IM; ++i) {
            if (EPI == 1 && TRV && bn >= N - 1024) {
                // transposed V store: [bh][dk][s], 4 consecutive s per lane
                const int which = bn >> 10;
                const int h = nl >> 6, dk = nl & 63;
                const int m0 = bm + wm + i * 16 + g * 4;
                const int bb = m0 >> 11, s0 = m0 & 2047;
                u16x4 pv;
#pragma unroll
                for (int r = 0; r < 4; ++r) pv[r] = f2b(acc[i][j2][r] + bv);
                *(u16x4*)(C + (size_t)which * 4194304 +
                          (((size_t)((bb << 4) + h)) * 64 + dk) * 2048 + s0) = pv;
            } else {
#pragma unroll
                for (int r = 0; r < 4; ++r) {
                    const int m = bm + wm + i * 16 + g * 4 + r;
                    float v = acc[i][j2][r] + bv;
                    if (EPI == 2) {
                        v += RF32 ? ((const float*)Rv)[(size_t)m * N + n]
                                  : b2f(((const ushort_t*)Rv)[(size_t)m * N + n]);
                    }
                    if (EPI == 3) v = v > 0.f ? v : 0.f;
                    if (EPI == 1) {
                        const int which = FUSED ? (bn >> 10) : 0;
                        if (QSC && which == 0)
                            v *= 0.18033688011112042f;   // log2(e)/8
                        const int bb = m >> 11, s = m & 2047;    // S = 2048
                        const int h = nl >> 6, dk = nl & 63;
                        const size_t dst = (size_t)which * 4194304 +
                            (((size_t)((bb << 4) + h)) * 2048 + s) * 64 + dk;
                        C[dst] = f2b(v);
                    } else {
                        ushort_t* Cp = SPLITC ? (m < 2048 ? C : C2) : C;
                        const int mr = SPLITC ? (m & 2047) : m;
                        Cp[(size_t)mr * N + n] = f2b(v);
                    }
                }
            }
        }
    }
}

// ---------------------------------------------------------------------------
// Flash attention v10. Q (pre-scaled by log2e/8), K: bf16 [B*H, S, 64];
// V: TRANSPOSED bf16 [B*H, 64, S]; O: bf16 [B*S, 1024].
// 64 q-rows/block (4 waves x 16). KVBLK=64, ring-2 (40 KB -> 4 blocks/CU).
// MERGED step: QK x8 MFMA (all 64 keys) -> exp x16 -> P-write x8 (two
// 512-entry copies of the conflict-free swizzled layout) -> ONE lgkmcnt ->
// pf x2 reads -> PV x8 MFMA. One barrier per 64 keys.
// Ring-2 hazard: prefetch writes slot s^1 while compute reads slot s
// (disjoint); slot reuse protected by the previous step's tail barrier.
// ---------------------------------------------------------------------------
template <bool CAUSAL>
__global__ __launch_bounds__(256) void flash_attn(
    const ushort_t* __restrict__ Q, const ushort_t* __restrict__ K,
    const ushort_t* __restrict__ V, ushort_t* __restrict__ O, int S)
{
    __shared__ __align__(16) ushort_t Kt[2][2][2048];
    __shared__ __align__(16) ushort_t Vt[2][2][2048];
    __shared__ __align__(16) ushort_t Pl[4096];

    const int tid = threadIdx.x, lane = tid & 63, w = tid >> 6;
    const int g = lane >> 4, qi = lane & 15;
    const int q2 = (qi >> 1) & 3;            // P-tile swizzle key
    const int bh = blockIdx.x;
    const int y = blockIdx.y;
    const int qb = CAUSAL ? ((y & 8) ? ((y & 16) ? 55 - y : 23 - y) : y) : y;
    const size_t base = (size_t)bh * S * 64;
    const int q0 = qb << 6;
    const int qw = q0 + w * 16;

    // K GLL source (wave w fills a Kt subtile's elems [w*512, w*512+512)):
    const int krow2 = ((w & 1) << 4) + (lane >> 2);
    const int kcol2 = ((w >> 1) << 5) + ((lane & 3) << 3);
    const ushort_t* Kp = K + base + (size_t)krow2 * 64 + kcol2;
    // V GLL source (V^T global [bh][d][s]; wave w fills Vt rows w*16..w*16+15):
    const ushort_t* Vp = V + base + (size_t)(w * 16 + (lane >> 2)) * 2048 +
                         ((lane & 3) << 3);

    bf16x8 qf0 = *(const bf16x8*)(Q + base + (size_t)(qw + qi) * 64 + g * 8);
    bf16x8 qf1 = *(const bf16x8*)(Q + base + (size_t)(qw + qi) * 64 + 32 + g * 8);
    // pin: forces the Q-load wait HERE (before any GLL issues) so the manual
    // vmcnt counts below only ever see GLLs
    asm volatile("" :: "v"(qf0), "v"(qf1));

    f32x4 oacc[4] = {};
    float lsum = 0.f;                        // per-lane partial of sum(p)

    // ntiles (32-key) is always even: causal 2qb+2, cross 64.
    const int nsteps = (CAUSAL ? ((q0 >> 5) + 2) : (S >> 5)) >> 1;   // >= 1

    // stage 64-key step st into ring slot c (4 GLLs/wave)
    auto stageKV = [&](int st, int c) {
        const int kn = st << 6;
        GLL(Kp + (size_t)kn * 64, &Kt[c][0][w * 512]);
        GLL(Kp + (size_t)(kn + 32) * 64, &Kt[c][1][w * 512]);
        GLL(Vp + kn, &Vt[c][0][w * 512]);
        GLL(Vp + kn + 32, &Vt[c][1][w * 512]);
    };

    // ---- prologue: stage step 0 into slot 0 ----
    stageKV(0, 0);
    asm volatile("s_waitcnt vmcnt(0)" ::: "memory");
    __builtin_amdgcn_s_barrier();
    __builtin_amdgcn_sched_barrier(0);

    for (int s = 0; s < nsteps; ++s) {
        const int c0 = s & 1;
        const bool pre = (s + 1 < nsteps);   // uniform across block

        // ---- issue prefetch of step s+1 into slot c0^1 ----
        if (pre) stageKV(s + 1, c0 ^ 1);
        __builtin_amdgcn_sched_barrier(0);

        // ---- QK^T for all 64 keys (8 MFMA); fragment i = sub*2 + tt ----
        f32x4 st4[4] = {};
        __builtin_amdgcn_s_setprio(1);
#pragma unroll
        for (int i = 0; i < 4; ++i) {
            const int sub = i >> 1, tt = i & 1;
            bf16x8 kf0 = *(const bf16x8*)(&Kt[c0][sub][(tt * 16 + qi) * 32 + g * 8]);
            bf16x8 kf1 = *(const bf16x8*)(&Kt[c0][sub][1024 + (tt * 16 + qi) * 32 + g * 8]);
            st4[i] = __builtin_amdgcn_mfma_f32_16x16x32_bf16(kf0, qf0, st4[i], 0, 0, 0);
            st4[i] = __builtin_amdgcn_mfma_f32_16x16x32_bf16(kf1, qf1, st4[i], 0, 0, 0);
        }
        __builtin_amdgcn_s_setprio(0);

        // ---- causal mask (exact per element) ----
        const int kb = s << 6;
        if (CAUSAL && (kb + 63 > qw)) {
#pragma unroll
            for (int i = 0; i < 4; ++i)
#pragma unroll
                for (int r = 0; r < 4; ++r)
                    if (kb + i * 16 + g * 4 + r > qw + qi) st4[i][r] = -1e30f;
        }

        // ---- no-max softmax: p = exp2(st) (Q pre-scaled by log2e/8) ----
        float p[4][4];
#pragma unroll
        for (int i = 0; i < 4; ++i)
#pragma unroll
            for (int r = 0; r < 4; ++r) {
                p[i][r] = EXP2(st4[i][r]);
                lsum += p[i][r];
            }

        // ---- P writes: two 512-entry copies of the swizzled layout ----
        ushort_t* pb = Pl + w * 1024;
#pragma unroll
        for (int i = 0; i < 4; ++i) {
            const int sub = i >> 1, tt = i & 1;
            unsigned lo, hi;
            asm("v_cvt_pk_bf16_f32 %0, %1, %2" : "=v"(lo) : "v"(p[i][0]), "v"(p[i][1]));
            asm("v_cvt_pk_bf16_f32 %0, %1, %2" : "=v"(hi) : "v"(p[i][2]), "v"(p[i][3]));
            const int swc = (tt * 2 + (g >> 1)) ^ q2;
            uint2 pw; pw.x = lo; pw.y = hi;
            *(uint2*)(pb + sub * 512 + qi * 32 + swc * 8 + (g & 1) * 4) = pw;
        }
        asm volatile("s_waitcnt lgkmcnt(0)" ::: "memory");
        __builtin_amdgcn_sched_barrier(0);
        bf16x8 pf0 = *(const bf16x8*)(pb + qi * 32 + ((g ^ q2) << 3));
        bf16x8 pf1 = *(const bf16x8*)(pb + 512 + qi * 32 + ((g ^ q2) << 3));

        // ---- PV for all 64 keys (8 MFMA) ----
        __builtin_amdgcn_s_setprio(1);
#pragma unroll
        for (int dt = 0; dt < 4; ++dt) {
            bf16x8 vf0 = *(const bf16x8*)(&Vt[c0][0][(dt * 16 + qi) * 32 + g * 8]);
            oacc[dt] = __builtin_amdgcn_mfma_f32_16x16x32_bf16(pf0, vf0, oacc[dt], 0, 0, 0);
        }
#pragma unroll
        for (int dt = 0; dt < 4; ++dt) {
            bf16x8 vf1 = *(const bf16x8*)(&Vt[c0][1][(dt * 16 + qi) * 32 + g * 8]);
            oacc[dt] = __builtin_amdgcn_mfma_f32_16x16x32_bf16(pf1, vf1, oacc[dt], 0, 0, 0);
        }
        __builtin_amdgcn_s_setprio(0);

        // ---- tail: drain prefetch (issued a full step earlier), barrier ----
        asm volatile("s_waitcnt vmcnt(0)" ::: "memory");
        __builtin_amdgcn_s_barrier();
        __builtin_amdgcn_sched_barrier(0);
    }

    lsum += __shfl_xor(lsum, 16);
    lsum += __shfl_xor(lsum, 32);
    float lv[4];
#pragma unroll
    for (int r = 0; r < 4; ++r) lv[r] = 1.f / __shfl(lsum, g * 4 + r, 16);

    const int b = bh >> 4, h = bh & 15;
#pragma unroll
    for (int dt = 0; dt < 4; ++dt)
#pragma unroll
        for (int r = 0; r < 4; ++r) {
            const int row = b * S + qw + g * 4 + r;
            const int col = (h << 6) + dt * 16 + qi;
            O[(size_t)row * 1024 + col] = f2b(oacc[dt][r] * lv[r]);
        }
}

// ---------------------------------------------------------------------------
// LayerNorm D=1024. X bf16 ws; gamma/beta fp32; OUT fp32 (final) or bf16.
// ---------------------------------------------------------------------------
template <bool OUTF32>
__global__ __launch_bounds__(256) void ln_kernel(
    const ushort_t* __restrict__ X, const float* __restrict__ gam,
    const float* __restrict__ bet, void* __restrict__ Yv)
{
    const int row = blockIdx.x, tid = threadIdx.x;
    const int lane = tid & 63, w = tid >> 6;
    const size_t off = (size_t)row * 1024 + tid * 4;

    u16x4 xv = *(const u16x4*)(X + off);
    float f[4];
#pragma unroll
    for (int i = 0; i < 4; ++i) f[i] = b2f(xv[i]);

    float s = f[0] + f[1] + f[2] + f[3];
    float sq = f[0] * f[0] + f[1] * f[1] + f[2] * f[2] + f[3] * f[3];
#pragma unroll
    for (int o = 32; o; o >>= 1) {
        s  += __shfl_xor(s, o);
        sq += __shfl_xor(sq, o);
    }
    __shared__ float red[8];
    if (lane == 0) { red[w] = s; red[4 + w] = sq; }
    __syncthreads();
    s  = red[0] + red[1] + red[2] + red[3];
    sq = red[4] + red[5] + red[6] + red[7];

    const float mu = s * (1.f / 1024.f);
    const float var = sq * (1.f / 1024.f) - mu * mu;
    const float rs = rsqrtf(var + 1e-5f);

    const float4 gv = *(const float4*)(gam + tid * 4);
    const float4 bv = *(const float4*)(bet + tid * 4);
    float y0 = (f[0] - mu) * rs * gv.x + bv.x;
    float y1 = (f[1] - mu) * rs * gv.y + bv.y;
    float y2 = (f[2] - mu) * rs * gv.z + bv.z;
    float y3 = (f[3] - mu) * rs * gv.w + bv.w;

    if (OUTF32) {
        float4 yv; yv.x = y0; yv.y = y1; yv.z = y2; yv.w = y3;
        *(float4*)((float*)Yv + off) = yv;
    } else {
        u16x4 yv;
        yv[0] = f2b(y0); yv[1] = f2b(y1); yv[2] = f2b(y2); yv[3] = f2b(y3);
        *(u16x4*)((ushort_t*)Yv + off) = yv;
    }
}

// ---------------------------------------------------------------------------
extern "C" void kernel_launch(void* const* d_in, const int* in_sizes, int n_in,
                              void* d_out, int out_size, void* d_ws, size_t ws_size,
                              hipStream_t stream)
{
    const float* x   = (const float*)d_in[0];
    const float* enc = (const float*)d_in[1];
    const float* Wq1 = (const float*)d_in[4];
    const float* bq1 = (const float*)d_in[5];
    const float* Wk1 = (const float*)d_in[6];
    const float* bk1 = (const float*)d_in[7];
    const float* Wv1 = (const float*)d_in[8];
    const float* bv1 = (const float*)d_in[9];
    const float* Wo1 = (const float*)d_in[10];
    const float* bo1 = (const float*)d_in[11];
    const float* Wq2 = (const float*)d_in[12];
    const float* bq2 = (const float*)d_in[13];
    const float* Wk2 = (const float*)d_in[14];
    const float* bk2 = (const float*)d_in[15];
    const float* Wv2 = (const float*)d_in[16];
    const float* bv2 = (const float*)d_in[17];
    const float* Wo2 = (const float*)d_in[18];
    const float* bo2 = (const float*)d_in[19];
    const float* Wf1 = (const float*)d_in[20];
    const float* bf1 = (const float*)d_in[21];
    const float* Wf2 = (const float*)d_in[22];
    const float* bf2 = (const float*)d_in[23];
    const float* gm1 = (const float*)d_in[24];
    const float* be1 = (const float*)d_in[25];
    const float* gm2 = (const float*)d_in[26];
    const float* be2 = (const float*)d_in[27];
    const float* gm3 = (const float*)d_in[28];
    const float* be3 = (const float*)d_in[29];

    float*    out = (float*)d_out;
    ushort_t* ws  = (ushort_t*)d_ws;
    ushort_t* F2  = (ushort_t*)d_out;   // 16 MB bf16 scratch until final LN

    const size_t E = (size_t)4096 * 1024;
    ushort_t* P0 = ws;
    ushort_t* P1 = ws + 1 * E;
    ushort_t* P2 = ws + 2 * E;
    ushort_t* P3 = ws + 3 * E;
    ushort_t* P4 = ws + 4 * E;
    ushort_t* Wb = ws + 5 * E;          // 16M bf16 weights (32 MB)

    const size_t M1 = 1048576;
    ushort_t* Wb_qkv1 = Wb;              // q1,k1,v1 contiguous
    ushort_t* Wb_o1   = Wb + 3 * M1;
    ushort_t* Wb_q2   = Wb + 4 * M1;
    ushort_t* Wb_kv2  = Wb + 5 * M1;     // k2,v2 contiguous
    ushort_t* Wb_o2   = Wb + 7 * M1;
    ushort_t* Wb_f1   = Wb + 8 * M1;
    ushort_t* Wb_f2   = Wb + 12 * M1;

    const dim3 blk(256);
    const dim3 gA(32, 32);               // x = bh, y = qb (balanced for causal)

    // ---- convert x, enc, all weights to bf16 ----
    conv_all<<<12288, blk, 0, stream>>>(x, enc, Wq1, Wk1, Wv1, Wo1, Wq2, Wk2,
                                        Wv2, Wo2, Wf1, Wf2, P3, P4, Wb);

    // ---- self attention ----
    // QKV fused: Q->P0 (pre-scaled), K->P1, V->P2 (V TRANSPOSED [bh][dk][s])
    gemm_bt<1, 128, false, true, false, false, true, true><<<dim3(24, 32), blk, 0, stream>>>(
        P3, nullptr, Wb_qkv1, bq1, bk1, bv1, nullptr, P0, nullptr, 4096, 3072, 1024);
    flash_attn<true><<<gA, blk, 0, stream>>>(P0, P1, P2, P3, 2048);
    gemm_bt<2, 64, true, false, false, false, false, false><<<dim3(8, 64), blk, 0, stream>>>(
        P3, nullptr, Wb_o1, bo1, bo1, bo1, x, P0, nullptr, 4096, 1024, 1024);
    ln_kernel<false><<<4096, blk, 0, stream>>>(P0, gm1, be1, P1);   // X1 = P1

    // ---- cross attention ----
    // cross-Q (pre-scaled) -> P0
    gemm_bt<1, 64, false, false, false, false, false, true><<<dim3(8, 64), blk, 0, stream>>>(
        P1, nullptr, Wb_q2, bq2, bq2, bq2, nullptr, P0, nullptr, 4096, 1024, 1024);
    // cross-KV fused: K->P2, V->P3 (V TRANSPOSED); QSC=false (which 0 is K!)
    gemm_bt<1, 128, false, true, false, false, true, false><<<dim3(16, 32), blk, 0, stream>>>(
        P4, nullptr, Wb_kv2, bk2, bv2, bv2, nullptr, P2, nullptr, 4096, 2048, 1024);
    flash_attn<false><<<gA, blk, 0, stream>>>(P0, P2, P3, P4, 2048);
    gemm_bt<2, 64, false, false, false, false, false, false><<<dim3(8, 64), blk, 0, stream>>>(
        P4, nullptr, Wb_o2, bo2, bo2, bo2, P1, P0, nullptr, 4096, 1024, 1024);
    ln_kernel<false><<<4096, blk, 0, stream>>>(P0, gm2, be2, P2);   // X2 = P2

    // ---- FFN ----
    gemm_bt<3, 128, false, false, false, true, false, false><<<dim3(32, 32), blk, 0, stream>>>(
        P2, nullptr, Wb_f1, bf1, bf1, bf1, nullptr, P0, F2, 4096, 4096, 1024);
    gemm_bt<2, 64, false, false, true, false, false, false><<<dim3(8, 64), blk, 0, stream>>>(
        P0, F2, Wb_f2, bf2, bf2, bf2, P2, P3, nullptr, 4096, 1024, 4096);
    ln_kernel<true><<<4096, blk, 0, stream>>>(P3, gm3, be3, out);
}